// Round 19
// baseline (320.510 us; speedup 1.0000x reference)
//
#include <hip/hip_runtime.h>

#define DEV __device__ __forceinline__

typedef __attribute__((ext_vector_type(4))) int i32x4;

// qi = 128*wq8(y) as int
DEV int wqi(float y) {
    int q = (int)rintf(y * 128.0f);
    return q < -127 ? -127 : (q > 127 ? 127 : q);
}
DEV unsigned encf(float f) { unsigned u = __float_as_uint(f); return (u & 0x80000000u) ? ~u : (u | 0x80000000u); }
DEV float decf(unsigned u) { return (u & 0x80000000u) ? __uint_as_float(u ^ 0x80000000u) : __uint_as_float(~u); }
DEV float wq8f(float x) {
    float q = rintf(x * 128.0f) * 0.0078125f;
    return fminf(fmaxf(q, -0.9921875f), 0.9921875f);
}

// async global->LDS, 16B per lane, dest = uniform base + lane*16 (linear)
#define GLOAD16(g, l) __builtin_amdgcn_global_load_lds( \
    (const __attribute__((address_space(1))) void*)(g), \
    (__attribute__((address_space(3))) void*)(l), 16, 0, 0)

// ---------------- i8 weight pack, LDS-staged coalesced transpose ----------------
struct PackDesc {
    const float* w0; const float* w1; uint4* dst;
    int OC0, OC1, CinW, K, noct, nch64u, ndup, gsz;
};
struct PackArgs { PackDesc d[11]; int bofs[12]; };

__global__ void __launch_bounds__(256) k_packall(PackArgs a) {
    __shared__ unsigned char sb[16 * (64 * 16 + 4)];
    const int b = blockIdx.x;
    int i = 0;
    #pragma unroll
    for (int j = 1; j < 11; ++j) if (b >= a.bofs[j]) i = j;
    const PackDesc D = a.d[i];
    const int b2 = b - a.bofs[i];
    const int oct = b2 % D.noct;
    const int ch64u = b2 / D.noct;
    const int K2 = D.K * D.K;
    const int NCHT = D.nch64u * D.ndup;
    const int row_elems = 64 * K2;
    const int SSTR = row_elems + 4;
    const int QR = row_elems / 4;
    const int NQ = 16 * QR;
    const int cin0 = ch64u * 64;
    const int tid = threadIdx.x;
    const int og = oct / D.gsz, ol = oct % D.gsz;

    for (int q = tid; q < NQ; q += 256) {
        const int r = q / QR, j = q - r * QR;
        const int oc = oct * 16 + r;
        const float* src = nullptr; int oci = 0;
        if (oc < D.OC0) { src = D.w0; oci = oc; }
        else if (oc < D.OC0 + D.OC1) { src = D.w1; oci = oc - D.OC0; }
        const int e0 = j * 4;
        float v[4] = {0.f, 0.f, 0.f, 0.f};
        if (src != nullptr) {
            const float* p = src + ((size_t)oci * D.CinW + cin0) * K2 + e0;
            const int cin_last = cin0 + (e0 + 3) / K2;
            if (cin_last < D.CinW) {
                const float4 f4 = *(const float4*)p;
                v[0] = f4.x; v[1] = f4.y; v[2] = f4.z; v[3] = f4.w;
            } else {
                #pragma unroll
                for (int e = 0; e < 4; ++e) {
                    const int cin = cin0 + (e0 + e) / K2;
                    if (cin < D.CinW) v[e] = p[e];
                }
            }
        }
        unsigned pk = 0;
        #pragma unroll
        for (int e = 0; e < 4; ++e) pk |= ((unsigned)(wqi(v[e]) & 255)) << (e * 8);
        *(unsigned*)&sb[r * SSTR + e0] = pk;
    }
    __syncthreads();

    const int outN = K2 * 64;
    for (int idx = tid; idx < outN; idx += 256) {
        const int kpos = idx >> 6, lane = idx & 63;
        const int l15 = lane & 15, g = lane >> 4;
        unsigned wd[4] = {0u, 0u, 0u, 0u};
        #pragma unroll
        for (int e = 0; e < 16; ++e) {
            const unsigned bval = sb[l15 * SSTR + (g * 16 + e) * K2 + kpos];
            wd[e >> 2] |= bval << ((e & 3) * 8);
        }
        uint4 u; u.x = wd[0]; u.y = wd[1]; u.z = wd[2]; u.w = wd[3];
        for (int d = 0; d < D.ndup; ++d) {
            const int ch64 = ch64u + d * D.nch64u;
            D.dst[((size_t)((og * NCHT + ch64) * K2 + kpos) * D.gsz + ol) * 64 + lane] = u;
        }
    }
}

// ---------------- fused prologue: feat/zbuf init + psum slice0 zero + cat zfills ----------------
__global__ void __launch_bounds__(256) k_prep(unsigned* __restrict__ feat, uint4* __restrict__ zbuf,
                                              uint4* __restrict__ ps0,
                                              uint4* __restrict__ z1, uint4* __restrict__ z2,
                                              uint4* __restrict__ z3) {
    int b = blockIdx.x;
    const int tid = threadIdx.x;
    uint4 z; z.x = z.y = z.z = z.w = 0u;
    if (b == 0) {
        feat[tid] = encf(0.0f);
        if (tid < 64) zbuf[tid] = z;
        return;
    }
    b -= 1;
    if (b < 1024) { ps0[b * 256 + tid] = z; return; }
    b -= 1024;
    if (b < 1536) {
        const int i = b * 256 + tid;
        if (i < 393216) { const int pix = i / 3, j = i - pix * 3; z1[(size_t)pix * 7 + 4 + j] = z; }
        return;
    }
    b -= 1536;
    if (b < 768) {
        const int i = b * 256 + tid;
        if (i < 196608) { const int pix = i / 6, j = i - pix * 6; z2[(size_t)pix * 14 + 8 + j] = z; }
        return;
    }
    b -= 768;
    {
        const int i = b * 256 + tid;
        if (i < 81920) { const int pix = i / 10, j = i - pix * 10; z3[(size_t)pix * 26 + 16 + j] = z; }
    }
}

// ---------------- conv1: LDS-tiled f32 vector conv (exact chain), i8 out ----------------
__global__ void __launch_bounds__(256) k_conv1(const float* __restrict__ x, const float* __restrict__ w1,
                                               signed char* __restrict__ cat1) {
    __shared__ float sw2[36][64];
    __shared__ float sin_[4][17][17];
    const int tid = threadIdx.x;
    const int n = blockIdx.y;
    const int oh0 = (blockIdx.x >> 4) * 8, ow0 = (blockIdx.x & 15) * 8;
    for (int i = tid; i < 2304; i += 256) sw2[i % 36][i / 36] = wq8f(w1[i]);
    const int ih0 = oh0 * 2 - 1, iw0 = ow0 * 2 - 1;
    for (int i = tid; i < 4 * 289; i += 256) {
        const int c = i / 289, rem = i % 289, r = rem / 17, cc = rem % 17;
        const int ih = ih0 + r, iw = iw0 + cc;
        float v = 0.f;
        if ((unsigned)ih < 256u && (unsigned)iw < 256u) v = x[((size_t)(n * 4 + c) * 256 + ih) * 256 + iw];
        sin_[c][r][cc] = v;
    }
    __syncthreads();
    const int sp = tid & 63, ocg = tid >> 6;
    const int oh = sp >> 3, ow = sp & 7;
    float acc[16];
    #pragma unroll
    for (int j = 0; j < 16; ++j) acc[j] = 0.f;
    #pragma unroll
    for (int c = 0; c < 4; ++c)
    #pragma unroll
    for (int kh = 0; kh < 3; ++kh)
    #pragma unroll
    for (int kw = 0; kw < 3; ++kw) {
        const float v = sin_[c][oh * 2 + kh][ow * 2 + kw];
        const float4* wp4 = (const float4*)&sw2[c * 9 + kh * 3 + kw][ocg * 16];
        #pragma unroll
        for (int q = 0; q < 4; ++q) {
            const float4 wv = wp4[q];
            acc[q * 4 + 0] = fmaf(v, wv.x, acc[q * 4 + 0]);
            acc[q * 4 + 1] = fmaf(v, wv.y, acc[q * 4 + 1]);
            acc[q * 4 + 2] = fmaf(v, wv.z, acc[q * 4 + 2]);
            acc[q * 4 + 3] = fmaf(v, wv.w, acc[q * 4 + 3]);
        }
    }
    const size_t pix = ((size_t)(n * 128) + oh0 + oh) * 128 + ow0 + ow;
    unsigned wd[4] = {0u, 0u, 0u, 0u};
    #pragma unroll
    for (int j = 0; j < 16; ++j)
        wd[j >> 2] |= ((unsigned)(wqi(acc[j]) & 255)) << ((j & 3) * 8);
    uint4 u; u.x = wd[0]; u.y = wd[1]; u.z = wd[2]; u.w = wd[3];
    *(uint4*)(cat1 + pix * 112 + ocg * 16) = u;
}

__global__ void k_fc(const unsigned* __restrict__ feat, const float* __restrict__ wfc,
                     float* __restrict__ out) {
    int n = threadIdx.x;
    if (n < 8) {
        float s = 0.f;
        for (int c = 0; c < 32; ++c) s += decf(feat[n * 32 + c]) * wq8f(wfc[c]);
        out[n] = wq8f(s);
    }
}

// ---------------- K-split partial combiner (D digits x G same-scale groups) ----------------
template<int CMODE>
__global__ void __launch_bounds__(256) k_comb(const int* __restrict__ ps, int D, int G,
                                              int NP, int OC, double inv,
                                              signed char* __restrict__ dst, int dstr, int dch,
                                              const void* __restrict__ res, int rstr,
                                              signed char* __restrict__ dhl, int dhlstr,
                                              short* __restrict__ dj,
                                              int ohw, int OWW, int r0, int r1, int c0, int c1,
                                              int* __restrict__ zp) {
    const int t = blockIdx.x * 256 + threadIdx.x;
    const int opc = OC / 4;
    const int total = NP * opc;
    if (t >= total) return;
    const int pix = t / opc, oc0 = (t - pix * opc) * 4;
    const int sp = pix % ohw;
    const int oh = sp / OWW, ow = sp - oh * OWW;
    if (oh < r0 || oh > r1 || ow < c0 || ow > c1) return;
    const size_t base = (size_t)pix * OC + oc0;
    const size_t NPOC = (size_t)NP * OC;
    long v[4] = {0, 0, 0, 0};
    int sidx = 0;
    for (int d = 0; d < D; ++d) {
        long s0 = 0, s1 = 0, s2 = 0, s3 = 0;
        for (int g = 0; g < G; ++g, ++sidx) {
            const int4 p = *(const int4*)(ps + sidx * NPOC + base);
            s0 += p.x; s1 += p.y; s2 += p.z; s3 += p.w;
        }
        v[0] = v[0] * 256 + s0; v[1] = v[1] * 256 + s1;
        v[2] = v[2] * 256 + s2; v[3] = v[3] * 256 + s3;
    }
    if (zp) { int4 z; z.x = z.y = z.z = z.w = 0; *(int4*)(zp + base) = z; }
    if constexpr (CMODE == 0) {
        unsigned pk = 0;
        #pragma unroll
        for (int j = 0; j < 4; ++j)
            pk |= (unsigned)(wqi((float)((double)v[j] * inv)) & 255) << (j * 8);
        *(unsigned*)(dst + (size_t)pix * dstr + dch + oc0) = pk;
    } else {
        #pragma unroll
        for (int j = 0; j < 4; ++j) {
            const int qi = wqi((float)((double)v[j] * inv));
            const int oc = oc0 + j;
            if constexpr (CMODE == 1) {
                const int rv = (int)((const signed char*)res)[(size_t)pix * rstr + oc];
                const int jj = (128 - qi) * rv;
                const int d0 = ((jj + 128) & 255) - 128;
                const int t1 = (jj - d0) >> 8;
                dhl[(size_t)pix * dhlstr + oc] = (signed char)t1;
                dhl[(size_t)pix * dhlstr + 512 + oc] = (signed char)d0;
                dj[(size_t)pix * 512 + oc] = (short)jj;
            } else {
                const int rv = (int)((const short*)res)[(size_t)pix * rstr + oc];
                const int jj = (128 - qi) * rv;
                const int d0 = ((jj + 128) & 255) - 128;
                const int t1 = (jj - d0) >> 8;
                const int d1 = ((t1 + 128) & 255) - 128;
                const int d2 = (t1 - d1) >> 8;
                dhl[(size_t)pix * dhlstr + oc] = (signed char)d2;
                dhl[(size_t)pix * dhlstr + 512 + oc] = (signed char)d1;
                dhl[(size_t)pix * dhlstr + 1024 + oc] = (signed char)d0;
            }
        }
    }
}

// ---------------- implicit-GEMM i8 MFMA conv ----------------
// AM = M sub-tiles per wave (each B fragment feeds AM MFMAs in registers ->
// B bytes/MAC = 1/(16*AM*2)); WM1/WN4 gives 4 distinct oc-groups per block.
// TH = WM*AM*2. MODE 0: dst=i8; 2: feat max; 3: i32 slice psum; 4: atomicAdd psum.
template<int K, int STR, int WM, int WN, int BN, int AM, int CHQ, int NBUF, int MODE>
__global__ void __launch_bounds__(256) k_mconv(
    const signed char* __restrict__ s0, int Ctot, int st0,
    int S, int padeff,
    const uint4* __restrict__ wqp, int nchtot,
    signed char* __restrict__ dst, int dstr, int dch,
    unsigned* __restrict__ feat, int* __restrict__ ps,
    const signed char* __restrict__ zbuf,
    int OCv, int OH, int OW, int TILES_W, int nch,
    int NT, int NOCG, int swzq, int ORD, int ohb, int owb)
{
    constexpr int TH = WM * AM * 2;
    constexpr int RH = (TH - 1) * STR + K, RW = 7 * STR + K;
    constexpr int UNITS = CHQ / 16;
    constexpr int UPPS = UNITS + 1;
    constexpr int NKC = CHQ / 64;
    constexpr int K2 = K * K;
    constexpr int NUS = RH * RW * UPPS;
    constexpr int ROUNDS = (NUS + 255) / 256;
    constexpr int NUPS = ROUNDS * 256;
    constexpr int AHEAD = NBUF - 1;
    __shared__ uint4 lds[NBUF * NUPS];
    __shared__ int sred[4][2][16];

    const int tid = threadIdx.x, lane = tid & 63, w = tid >> 6;
    const int wm = w % WM, wn = w / WM;
    const int l15 = lane & 15, g = lane >> 4;

    const int b = blockIdx.x;
    const int work = (b & 7) * swzq + (b >> 3);
    int tile, n, ocg, slice;
    if (ORD == 0) {
        ocg = work % NOCG; const int t2 = work / NOCG;
        tile = t2 % NT; const int t3 = t2 / NT;
        n = t3 & 7; slice = t3 >> 3;
    } else {
        tile = work % NT; const int t2 = work / NT;
        n = t2 & 7; const int t3 = t2 >> 3;
        ocg = t3 % NOCG; slice = t3 / NOCG;
    }
    const int cin_off = slice * nch * CHQ;
    const int group = ocg * WN + wn;

    const int tileh = tile / TILES_W, tilew = tile % TILES_W;
    const int oh0 = ohb + tileh * TH, ow0 = owb + tilew * 8;
    const int ih0 = oh0 * STR - padeff, iw0 = ow0 * STR - padeff;
    const int blk_oct0 = ocg * (WN * BN);

    int pixb[AM];
    #pragma unroll
    for (int am = 0; am < AM; ++am) {
        const int sp = (wm * AM + am) * 16 + l15;
        pixb[am] = ((sp >> 3) * STR) * RW + (sp & 7) * STR;
    }

    // hoisted staging addresses: per-rd base pointer + channel-limit
    int climit[ROUNDS];
    const signed char* gpb[ROUNDS];
    #pragma unroll
    for (int rd = 0; rd < ROUNDS; ++rd) {
        const int d = rd * 256 + tid;
        int cl = -1;
        const signed char* gb = zbuf;
        if (d < NUS) {
            const int pix = d / UPPS;
            const int u = d - pix * UPPS;
            const int r = pix / RW, c = pix - r * RW;
            const int ih = ih0 + r, iw = iw0 + c;
            if (u < UNITS && (unsigned)ih < (unsigned)S && (unsigned)iw < (unsigned)S) {
                cl = Ctot - cin_off - u * 16;
                gb = s0 + (((size_t)n * S + ih) * S + iw) * st0 + cin_off + u * 16;
            }
        }
        climit[rd] = cl; gpb[rd] = gb;
    }

    i32x4 acc[AM][BN];
    #pragma unroll
    for (int am = 0; am < AM; ++am)
        #pragma unroll
        for (int bn = 0; bn < BN; ++bn) acc[am][bn] = (i32x4){0, 0, 0, 0};

    auto issue = [&](int ch, int buf) {
        uint4* lb = &lds[buf * NUPS];
        const int chv = ch * CHQ;
        #pragma unroll
        for (int rd = 0; rd < ROUNDS; ++rd) {
            const signed char* gp = (chv < climit[rd]) ? (gpb[rd] + chv) : zbuf;
            GLOAD16(gp, lb + rd * 256 + (tid & ~63));
        }
    };

    #pragma unroll
    for (int i = 0; i < AHEAD; ++i) if (i < nch) issue(i, i % NBUF);

    for (int ch = 0; ch < nch; ++ch) {
        if (ch + AHEAD < nch) issue(ch + AHEAD, (ch + AHEAD) % NBUF);
        const int infl = (nch - 1 - ch < AHEAD) ? nch - 1 - ch : AHEAD;
        if (infl >= 2)      __builtin_amdgcn_s_waitcnt(0xF70 | (2 * ROUNDS));
        else if (infl == 1) __builtin_amdgcn_s_waitcnt(0xF70 | ROUNDS);
        else                __builtin_amdgcn_s_waitcnt(0xF70);
        __builtin_amdgcn_s_barrier();
        __builtin_amdgcn_sched_barrier(0);
        const int bufo = (ch % NBUF) * NUPS;
        int pbs[AM];
        #pragma unroll
        for (int am = 0; am < AM; ++am) pbs[am] = bufo + pixb[am] * UPPS + g;
        const uint4* wrow = wqp + ((size_t)(group * nchtot + (slice * nch + ch) * NKC) * K2 * BN) * 64 + lane;
        #pragma unroll
        for (int kpos = 0; kpos < K2; ++kpos) {
            const int kh = kpos / K, kw = kpos % K;
            const int po = (kh * RW + kw) * UPPS;
            #pragma unroll
            for (int kc = 0; kc < NKC; ++kc) {
                i32x4 bfr[BN];
                #pragma unroll
                for (int bn = 0; bn < BN; ++bn) {
                    union { uint4 u; i32x4 v; } bu;
                    bu.u = wrow[(kc * K2 * BN + kpos * BN + bn) * 64];
                    bfr[bn] = bu.v;
                }
                #pragma unroll
                for (int am = 0; am < AM; ++am) {
                    union { uint4 u; i32x4 v; } a0;
                    a0.u = lds[pbs[am] + po + kc * 4];
                    #pragma unroll
                    for (int bn = 0; bn < BN; ++bn)
                        acc[am][bn] = __builtin_amdgcn_mfma_i32_16x16x64_i8(a0.v, bfr[bn], acc[am][bn], 0, 0, 0);
                }
            }
        }
        __builtin_amdgcn_sched_barrier(0);
        __builtin_amdgcn_s_barrier();
    }

    if constexpr (MODE == 2) {
        #pragma unroll
        for (int bn = 0; bn < BN; ++bn) {
            int m = (int)0x80000000;
            #pragma unroll
            for (int am = 0; am < AM; ++am)
                #pragma unroll
                for (int rg = 0; rg < 4; ++rg) {
                    const int sp = (wm * AM + am) * 16 + g * 4 + rg;
                    const int oh = oh0 + (sp >> 3), ow = ow0 + (sp & 7);
                    const int v = acc[am][bn][rg];
                    if (oh < OH && ow < OW && v > m) m = v;
                }
            int o = __shfl_xor(m, 16); if (o > m) m = o;
            o = __shfl_xor(m, 32); if (o > m) m = o;
            if (lane < 16) sred[w][bn][l15] = m;
        }
        __syncthreads();
        if (tid < BN * 16) {
            const int bn = tid >> 4, l = tid & 15;
            int mm = sred[0][bn][l];
            #pragma unroll
            for (int i = 1; i < WM * WN; ++i) { const int o = sred[i][bn][l]; if (o > mm) mm = o; }
            const float y = (float)mm * (1.f / 16384.f);
            const float v = (float)wqi(y) * 0.0078125f;
            atomicMax(&feat[n * 32 + (blk_oct0 + bn) * 16 + l], encf(v));
        }
    } else if constexpr (MODE == 3) {
        #pragma unroll
        for (int am = 0; am < AM; ++am)
        #pragma unroll
        for (int bn = 0; bn < BN; ++bn)
        #pragma unroll
        for (int rg = 0; rg < 4; ++rg) {
            const int sp = (wm * AM + am) * 16 + g * 4 + rg;
            const int oh = oh0 + (sp >> 3), ow = ow0 + (sp & 7);
            const int oc = (blk_oct0 + wn * BN + bn) * 16 + l15;
            if (oh < OH && ow < OW && oc < OCv) {
                ps[(((size_t)slice * 8 + n) * OH * OW + (size_t)oh * OW + ow) * OCv + oc] = acc[am][bn][rg];
            }
        }
    } else if constexpr (MODE == 4) {
        #pragma unroll
        for (int am = 0; am < AM; ++am)
        #pragma unroll
        for (int bn = 0; bn < BN; ++bn)
        #pragma unroll
        for (int rg = 0; rg < 4; ++rg) {
            const int sp = (wm * AM + am) * 16 + g * 4 + rg;
            const int oh = oh0 + (sp >> 3), ow = ow0 + (sp & 7);
            const int oc = (blk_oct0 + wn * BN + bn) * 16 + l15;
            if (oh < OH && ow < OW && oc < OCv) {
                atomicAdd(&ps[((size_t)n * OH * OW + (size_t)oh * OW + ow) * OCv + oc], acc[am][bn][rg]);
            }
        }
    } else {
        #pragma unroll
        for (int am = 0; am < AM; ++am)
        #pragma unroll
        for (int bn = 0; bn < BN; ++bn)
        #pragma unroll
        for (int rg = 0; rg < 4; ++rg) {
            const int sp = (wm * AM + am) * 16 + g * 4 + rg;
            const int oh = oh0 + (sp >> 3), ow = ow0 + (sp & 7);
            const int oc = (blk_oct0 + wn * BN + bn) * 16 + l15;
            if (oh < OH && ow < OW && oc < OCv) {
                const size_t pixo = (size_t)(n * OH + oh) * OW + ow;
                const float y = (float)acc[am][bn][rg] * (1.f / 16384.f);
                dst[pixo * dstr + dch + oc] = (signed char)wqi(y);
            }
        }
    }
}

extern "C" void kernel_launch(void* const* d_in, const int* in_sizes, int n_in,
                              void* d_out, int out_size, void* d_ws, size_t ws_size,
                              hipStream_t stream)
{
    (void)in_sizes; (void)n_in; (void)out_size; (void)ws_size;
    const float* x = (const float*)d_in[0];
    const float* wfc = (const float*)d_in[16];
    float* out = (float*)d_out;

    char* ws = (char*)d_ws;
    size_t off = 0;
    auto alloc = [&](size_t bytes) { char* p = ws + off; off += (bytes + 255) & ~(size_t)255; return p; };

    // {w0 idx, OC0, w1 idx, OC1, CinW, K, noct, nch64u, ndup, gsz(=BN)}
    struct PH { int i0, OC0, i1, OC1, CinW, K, noct, nch64u, ndup, gsz; };
    static const PH ph[11] = {
        {2, 128, -1, 0,  64, 3,  8, 1, 1, 2},   // 0 conv2
        {3, 256, -1, 0, 128, 3, 16, 2, 1, 2},   // 1 conv3
        {4, 512, -1, 0, 256, 3, 32, 4, 1, 2},   // 2 conv4
        {5, 512, -1, 0, 512, 3, 32, 8, 1, 2},   // 3 r11
        {6, 512, -1, 0, 512, 3, 32, 8, 1, 2},   // 4 r12
        {7, 512, -1, 0, 512, 3, 32, 8, 2, 2},   // 5 r21 (2 digit copies)
        {8, 512, -1, 0, 512, 3, 32, 8, 1, 2},   // 6 r22
        {9, 128, 12, 32, 512, 4, 16, 8, 3, 2},  // 7 L3 = wd3|wu43 (3 digit copies, noct padded 10->16)
        {10, 64, 13, 32, 416, 4,  6, 7, 1, 2},  // 8 L2 = wd2|wu32
        {11,  4, 14, 32, 224, 4,  3, 4, 1, 3},  // 9 L1 = wd1|wu21 (+12 zero oc)
        {15, 32, -1, 0, 100, 4,  2, 2, 1, 2}};  // 10 u10

    PackArgs pa;
    int bacc = 0;
    uint4* wp[11];
    for (int i = 0; i < 11; ++i) {
        const int nch64 = ph[i].nch64u * ph[i].ndup;
        const int nel = nch64 * ph[i].K * ph[i].K * ph[i].noct * 64;
        wp[i] = (uint4*)alloc((size_t)nel * 16);
        pa.d[i].w0 = (const float*)d_in[ph[i].i0];
        pa.d[i].w1 = (ph[i].i1 >= 0) ? (const float*)d_in[ph[i].i1] : nullptr;
        pa.d[i].dst = wp[i];
        pa.d[i].OC0 = ph[i].OC0; pa.d[i].OC1 = ph[i].OC1;
        pa.d[i].CinW = ph[i].CinW; pa.d[i].K = ph[i].K; pa.d[i].noct = ph[i].noct;
        pa.d[i].nch64u = ph[i].nch64u; pa.d[i].ndup = ph[i].ndup;
        pa.d[i].gsz = ph[i].gsz;
        pa.bofs[i] = bacc;
        bacc += ph[i].noct * ph[i].nch64u;
    }
    pa.bofs[11] = bacc;

    signed char* cat1b = (signed char*)alloc((size_t)8*128*128*112);  // c1|d1|f2|pad12
    signed char* cat2b = (signed char*)alloc((size_t)8*64*64*224);    // c2|d2|f3
    signed char* cat3b = (signed char*)alloc((size_t)8*32*32*416);    // c3|d3|f4
    signed char* c4b   = (signed char*)alloc((size_t)8*16*16*512);
    signed char* r11b  = (signed char*)alloc((size_t)8*16*16*512);    // also r21 out
    signed char* r12d  = (signed char*)alloc((size_t)8*16*16*1024);   // r12 digits hi|lo
    short*       r12j  = (short*)alloc((size_t)8*16*16*512 * 2);      // r12 as i16 j (gate res)
    signed char* r22d  = (signed char*)alloc((size_t)8*16*16*1536);   // r22 digits j2|j1|j0
    int*         psum  = (int*)alloc((size_t)8*8*16*16*512 * 4);      // K-split partials (33.5MB)
    unsigned*    featb = (unsigned*)alloc(256 * 4);
    uint4*       zbuf  = (uint4*)alloc(1024);

    k_packall<<<dim3((unsigned)bacc), dim3(256), 0, stream>>>(pa);
    k_prep<<<dim3(3649), 256, 0, stream>>>(featb, zbuf, (uint4*)psum,
        (uint4*)cat1b, (uint4*)cat2b, (uint4*)cat3b);
    k_conv1<<<dim3(256, 8), dim3(256), 0, stream>>>(x, (const float*)d_in[1], cat1b);

    const signed char* zb = (const signed char*)zbuf;
    const void* nv = nullptr;
    const int BIG = 1 << 30;

    // conv2: cat1 ch0..64 -> cat2 ch0..128   AM2; NT=64 NOCG=2 total=1024  ORD0
    k_mconv<3,2,2,2,2,2,64,1,0><<<dim3(1024), 256, 0, stream>>>(
        cat1b,64,112, 128,1, wp[0],1, cat2b,224,0, nullptr,nullptr, zb,
        128,64,64,8, 1, 64,2,128, 0, 0,0);
    // conv3: cat2 -> cat3 ch0..256           AM2; NT=16 NOCG=4 total=512  ORD0
    k_mconv<3,2,2,2,2,2,64,2,0><<<dim3(512), 256, 0, stream>>>(
        cat2b,128,224, 64,1, wp[1],2, cat3b,416,0, nullptr,nullptr, zb,
        256,32,32,4, 2, 16,4,64, 0, 0,0);
    // conv4: WM1/WN4/AM4, 4 atomic K-slices; NT=4 TILES_W=2 NOCG=4 total=512  ORD1
    k_mconv<3,2,1,4,2,4,64,1,4><<<dim3(512), 256, 0, stream>>>(
        cat3b,256,416, 32,1, wp[2],4, nullptr,0,0, nullptr,(int*)psum, zb,
        512,16,16,2, 1, 4,4,64, 1, 0,0);
    k_comb<0><<<dim3(1024), 256, 0, stream>>>(psum,1,1, 2048,512, 1.0/16384.0, c4b,512,0, nv,0, nullptr,0,nullptr,
        256,16, 0,BIG,0,BIG, psum);   // zero for r11
    // r11: WM1/WN4/AM4, 8 atomic K-slices of 64; NT=4 NOCG=4 total=1024 swzq=128 ORD1
    k_mconv<3,1,1,4,2,4,64,1,4><<<dim3(1024), 256, 0, stream>>>(
        c4b,512,512, 16,1, wp[3],8, nullptr,0,0, nullptr,psum, zb,
        512,16,16,2, 1, 4,4,128, 1, 0,0);
    k_comb<0><<<dim3(1024), 256, 0, stream>>>(psum,1,1, 2048,512, 1.0/16384.0, r11b,512,0, nv,0, nullptr,0,nullptr,
        256,16, 0,BIG,0,BIG, psum);   // zero for r12
    // r12: WM1/WN4/AM4, 8 atomic K-slices; total=1024 ORD1
    k_mconv<3,1,1,4,2,4,64,1,4><<<dim3(1024), 256, 0, stream>>>(
        r11b,512,512, 16,1, wp[4],8, nullptr,0,0, nullptr,psum, zb,
        512,16,16,2, 1, 4,4,128, 1, 0,0);
    k_comb<1><<<dim3(1024), 256, 0, stream>>>(psum,1,1, 2048,512, 1.0/16384.0, nullptr,0,0, c4b,512, r12d,1024,r12j,
        256,16, 0,BIG,0,BIG, nullptr);   // r21 overwrites psum slices
    // r21: WM1/WN4/AM4, digits input, 8 slices of 128 (4 per digit, MODE3); total=1024 ORD1
    k_mconv<3,1,1,4,2,4,128,1,3><<<dim3(1024), 256, 0, stream>>>(
        r12d,1024,1024, 16,1, wp[5],16, nullptr,0,0, nullptr,psum, zb,
        512,16,16,2, 1, 4,4,128, 1, 0,0);
    k_comb<0><<<dim3(1024), 256, 0, stream>>>(psum,2,4, 2048,512, 1.0/2097152.0, r11b,512,0, nv,0, nullptr,0,nullptr,
        256,16, 0,BIG,0,BIG, psum);   // zero for r22
    // r22: WM1/WN4/AM4, 8 atomic K-slices; total=1024 ORD1
    k_mconv<3,1,1,4,2,4,64,1,4><<<dim3(1024), 256, 0, stream>>>(
        r11b,512,512, 16,1, wp[6],8, nullptr,0,0, nullptr,psum, zb,
        512,16,16,2, 1, 4,4,128, 1, 0,0);
    k_comb<2><<<dim3(1024), 256, 0, stream>>>(psum,1,1, 2048,512, 1.0/16384.0, nullptr,0,0, r12j,512, r22d,1536,nullptr,
        256,16, 0,BIG,0,BIG, nullptr);
    // L3: WM1/WN4/AM4, region [7,25], 6 slices = 3 digits x 2 halves (nch=2, CHQ128);
    // NT=9 (3x3 of 8x8), TILES_W=3, origin (7,7), NOCG=2 (noct padded 16); grid=864 swzq=108
    k_mconv<4,1,1,4,2,4,128,1,3><<<dim3(864), 256, 0, stream>>>(
        r22d,1536,1536, 16,10, wp[7],24, nullptr,0,0, nullptr,psum, zb,
        160,32,32,3, 2, 9,2,108, 1, 7,7);
    k_comb<0><<<dim3(1280), 256, 0, stream>>>(psum,3,2, 8192,160, 1.0/268435456.0, cat3b,416,256, nv,0, nullptr,0,nullptr,
        1024,32, 7,25,7,25, nullptr);
    // L2: [d2|f3], AM2, region [15,49]: NT=15 (3x5), TILES_W=5, origin (15,15); grid=360
    k_mconv<4,1,4,1,2,2,64,2,0><<<dim3(360), 256, 0, stream>>>(
        cat3b,416,416, 32,18, wp[8],7, cat2b,224,128, nullptr,nullptr, zb,
        96,64,64,5, 7, 15,3,45, 0, 15,15);
    // L1: [d1|f2|pad], AM2, region [31,97]: NT=45 (5x9), TILES_W=9, origin (31,31); grid=360
    k_mconv<4,1,4,1,3,2,64,2,0><<<dim3(360), 256, 0, stream>>>(
        cat2b,224,224, 64,34, wp[9],4, cat1b,112,64, nullptr,nullptr, zb,
        48,128,128,9, 4, 45,1,45, 0, 31,31);
    // u10 + fused global max-pool, AM2, region [63,197]: NT=153 (9x17), origin (63,63); grid=1224
    k_mconv<4,1,4,1,2,2,128,1,2><<<dim3(1224), 256, 0, stream>>>(
        cat1b,112,112, 128,66, wp[10],2, nullptr,0,0, featb,nullptr, zb,
        32,257,257,17, 1, 153,1,153, 0, 63,63);
    // FC
    k_fc<<<dim3(1), dim3(64), 0, stream>>>(featb, wfc, out);
}

// Round 20
// 294.743 us; speedup vs baseline: 1.0874x; 1.0874x over previous
//
#include <hip/hip_runtime.h>

#define DEV __device__ __forceinline__

typedef __attribute__((ext_vector_type(4))) int i32x4;

// qi = 128*wq8(y) as int
DEV int wqi(float y) {
    int q = (int)rintf(y * 128.0f);
    return q < -127 ? -127 : (q > 127 ? 127 : q);
}
DEV unsigned encf(float f) { unsigned u = __float_as_uint(f); return (u & 0x80000000u) ? ~u : (u | 0x80000000u); }
DEV float decf(unsigned u) { return (u & 0x80000000u) ? __uint_as_float(u ^ 0x80000000u) : __uint_as_float(~u); }
DEV float wq8f(float x) {
    float q = rintf(x * 128.0f) * 0.0078125f;
    return fminf(fmaxf(q, -0.9921875f), 0.9921875f);
}

// async global->LDS, 16B per lane, dest = uniform base + lane*16 (linear)
#define GLOAD16(g, l) __builtin_amdgcn_global_load_lds( \
    (const __attribute__((address_space(1))) void*)(g), \
    (__attribute__((address_space(3))) void*)(l), 16, 0, 0)

// ---------------- i8 weight pack, LDS-staged coalesced transpose ----------------
struct PackDesc {
    const float* w0; const float* w1; uint4* dst;
    int OC0, OC1, CinW, K, noct, nch64u, ndup, gsz;
};
struct PackArgs { PackDesc d[11]; int bofs[12]; };

__global__ void __launch_bounds__(256) k_packall(PackArgs a) {
    __shared__ unsigned char sb[16 * (64 * 16 + 4)];
    const int b = blockIdx.x;
    int i = 0;
    #pragma unroll
    for (int j = 1; j < 11; ++j) if (b >= a.bofs[j]) i = j;
    const PackDesc D = a.d[i];
    const int b2 = b - a.bofs[i];
    const int oct = b2 % D.noct;
    const int ch64u = b2 / D.noct;
    const int K2 = D.K * D.K;
    const int NCHT = D.nch64u * D.ndup;
    const int row_elems = 64 * K2;
    const int SSTR = row_elems + 4;
    const int QR = row_elems / 4;
    const int NQ = 16 * QR;
    const int cin0 = ch64u * 64;
    const int tid = threadIdx.x;
    const int og = oct / D.gsz, ol = oct % D.gsz;

    for (int q = tid; q < NQ; q += 256) {
        const int r = q / QR, j = q - r * QR;
        const int oc = oct * 16 + r;
        const float* src = nullptr; int oci = 0;
        if (oc < D.OC0) { src = D.w0; oci = oc; }
        else if (oc < D.OC0 + D.OC1) { src = D.w1; oci = oc - D.OC0; }
        const int e0 = j * 4;
        float v[4] = {0.f, 0.f, 0.f, 0.f};
        if (src != nullptr) {
            const float* p = src + ((size_t)oci * D.CinW + cin0) * K2 + e0;
            const int cin_last = cin0 + (e0 + 3) / K2;
            if (cin_last < D.CinW) {
                const float4 f4 = *(const float4*)p;
                v[0] = f4.x; v[1] = f4.y; v[2] = f4.z; v[3] = f4.w;
            } else {
                #pragma unroll
                for (int e = 0; e < 4; ++e) {
                    const int cin = cin0 + (e0 + e) / K2;
                    if (cin < D.CinW) v[e] = p[e];
                }
            }
        }
        unsigned pk = 0;
        #pragma unroll
        for (int e = 0; e < 4; ++e) pk |= ((unsigned)(wqi(v[e]) & 255)) << (e * 8);
        *(unsigned*)&sb[r * SSTR + e0] = pk;
    }
    __syncthreads();

    const int outN = K2 * 64;
    for (int idx = tid; idx < outN; idx += 256) {
        const int kpos = idx >> 6, lane = idx & 63;
        const int l15 = lane & 15, g = lane >> 4;
        unsigned wd[4] = {0u, 0u, 0u, 0u};
        #pragma unroll
        for (int e = 0; e < 16; ++e) {
            const unsigned bval = sb[l15 * SSTR + (g * 16 + e) * K2 + kpos];
            wd[e >> 2] |= bval << ((e & 3) * 8);
        }
        uint4 u; u.x = wd[0]; u.y = wd[1]; u.z = wd[2]; u.w = wd[3];
        for (int d = 0; d < D.ndup; ++d) {
            const int ch64 = ch64u + d * D.nch64u;
            D.dst[((size_t)((og * NCHT + ch64) * K2 + kpos) * D.gsz + ol) * 64 + lane] = u;
        }
    }
}

// ---------------- fused prologue: feat/zbuf init + psum slice0 zero + cat zfills ----------------
__global__ void __launch_bounds__(256) k_prep(unsigned* __restrict__ feat, uint4* __restrict__ zbuf,
                                              uint4* __restrict__ ps0,
                                              uint4* __restrict__ z1, uint4* __restrict__ z2,
                                              uint4* __restrict__ z3) {
    int b = blockIdx.x;
    const int tid = threadIdx.x;
    uint4 z; z.x = z.y = z.z = z.w = 0u;
    if (b == 0) {
        feat[tid] = encf(0.0f);
        if (tid < 64) zbuf[tid] = z;
        return;
    }
    b -= 1;
    if (b < 1024) { ps0[b * 256 + tid] = z; return; }
    b -= 1024;
    if (b < 1536) {
        const int i = b * 256 + tid;
        if (i < 393216) { const int pix = i / 3, j = i - pix * 3; z1[(size_t)pix * 7 + 4 + j] = z; }
        return;
    }
    b -= 1536;
    if (b < 768) {
        const int i = b * 256 + tid;
        if (i < 196608) { const int pix = i / 6, j = i - pix * 6; z2[(size_t)pix * 14 + 8 + j] = z; }
        return;
    }
    b -= 768;
    {
        const int i = b * 256 + tid;
        if (i < 81920) { const int pix = i / 10, j = i - pix * 10; z3[(size_t)pix * 26 + 16 + j] = z; }
    }
}

// ---------------- conv1: LDS-tiled f32 vector conv (exact chain), i8 out ----------------
__global__ void __launch_bounds__(256) k_conv1(const float* __restrict__ x, const float* __restrict__ w1,
                                               signed char* __restrict__ cat1) {
    __shared__ float sw2[36][64];
    __shared__ float sin_[4][17][17];
    const int tid = threadIdx.x;
    const int n = blockIdx.y;
    const int oh0 = (blockIdx.x >> 4) * 8, ow0 = (blockIdx.x & 15) * 8;
    for (int i = tid; i < 2304; i += 256) sw2[i % 36][i / 36] = wq8f(w1[i]);
    const int ih0 = oh0 * 2 - 1, iw0 = ow0 * 2 - 1;
    for (int i = tid; i < 4 * 289; i += 256) {
        const int c = i / 289, rem = i % 289, r = rem / 17, cc = rem % 17;
        const int ih = ih0 + r, iw = iw0 + cc;
        float v = 0.f;
        if ((unsigned)ih < 256u && (unsigned)iw < 256u) v = x[((size_t)(n * 4 + c) * 256 + ih) * 256 + iw];
        sin_[c][r][cc] = v;
    }
    __syncthreads();
    const int sp = tid & 63, ocg = tid >> 6;
    const int oh = sp >> 3, ow = sp & 7;
    float acc[16];
    #pragma unroll
    for (int j = 0; j < 16; ++j) acc[j] = 0.f;
    #pragma unroll
    for (int c = 0; c < 4; ++c)
    #pragma unroll
    for (int kh = 0; kh < 3; ++kh)
    #pragma unroll
    for (int kw = 0; kw < 3; ++kw) {
        const float v = sin_[c][oh * 2 + kh][ow * 2 + kw];
        const float4* wp4 = (const float4*)&sw2[c * 9 + kh * 3 + kw][ocg * 16];
        #pragma unroll
        for (int q = 0; q < 4; ++q) {
            const float4 wv = wp4[q];
            acc[q * 4 + 0] = fmaf(v, wv.x, acc[q * 4 + 0]);
            acc[q * 4 + 1] = fmaf(v, wv.y, acc[q * 4 + 1]);
            acc[q * 4 + 2] = fmaf(v, wv.z, acc[q * 4 + 2]);
            acc[q * 4 + 3] = fmaf(v, wv.w, acc[q * 4 + 3]);
        }
    }
    const size_t pix = ((size_t)(n * 128) + oh0 + oh) * 128 + ow0 + ow;
    unsigned wd[4] = {0u, 0u, 0u, 0u};
    #pragma unroll
    for (int j = 0; j < 16; ++j)
        wd[j >> 2] |= ((unsigned)(wqi(acc[j]) & 255)) << ((j & 3) * 8);
    uint4 u; u.x = wd[0]; u.y = wd[1]; u.z = wd[2]; u.w = wd[3];
    *(uint4*)(cat1 + pix * 112 + ocg * 16) = u;
}

__global__ void k_fc(const unsigned* __restrict__ feat, const float* __restrict__ wfc,
                     float* __restrict__ out) {
    int n = threadIdx.x;
    if (n < 8) {
        float s = 0.f;
        for (int c = 0; c < 32; ++c) s += decf(feat[n * 32 + c]) * wq8f(wfc[c]);
        out[n] = wq8f(s);
    }
}

// ---------------- K-split partial combiner (D digits x G same-scale groups) ----------------
template<int CMODE>
__global__ void __launch_bounds__(256) k_comb(const int* __restrict__ ps, int D, int G,
                                              int NP, int OC, double inv,
                                              signed char* __restrict__ dst, int dstr, int dch,
                                              const void* __restrict__ res, int rstr,
                                              signed char* __restrict__ dhl, int dhlstr,
                                              short* __restrict__ dj,
                                              int ohw, int OWW, int r0, int r1, int c0, int c1,
                                              int* __restrict__ zp) {
    const int t = blockIdx.x * 256 + threadIdx.x;
    const int opc = OC / 4;
    const int total = NP * opc;
    if (t >= total) return;
    const int pix = t / opc, oc0 = (t - pix * opc) * 4;
    const int sp = pix % ohw;
    const int oh = sp / OWW, ow = sp - oh * OWW;
    if (oh < r0 || oh > r1 || ow < c0 || ow > c1) return;
    const size_t base = (size_t)pix * OC + oc0;
    const size_t NPOC = (size_t)NP * OC;
    long v[4] = {0, 0, 0, 0};
    int sidx = 0;
    for (int d = 0; d < D; ++d) {
        long s0 = 0, s1 = 0, s2 = 0, s3 = 0;
        for (int g = 0; g < G; ++g, ++sidx) {
            const int4 p = *(const int4*)(ps + sidx * NPOC + base);
            s0 += p.x; s1 += p.y; s2 += p.z; s3 += p.w;
        }
        v[0] = v[0] * 256 + s0; v[1] = v[1] * 256 + s1;
        v[2] = v[2] * 256 + s2; v[3] = v[3] * 256 + s3;
    }
    if (zp) { int4 z; z.x = z.y = z.z = z.w = 0; *(int4*)(zp + base) = z; }
    if constexpr (CMODE == 0) {
        unsigned pk = 0;
        #pragma unroll
        for (int j = 0; j < 4; ++j)
            pk |= (unsigned)(wqi((float)((double)v[j] * inv)) & 255) << (j * 8);
        *(unsigned*)(dst + (size_t)pix * dstr + dch + oc0) = pk;
    } else {
        #pragma unroll
        for (int j = 0; j < 4; ++j) {
            const int qi = wqi((float)((double)v[j] * inv));
            const int oc = oc0 + j;
            if constexpr (CMODE == 1) {
                const int rv = (int)((const signed char*)res)[(size_t)pix * rstr + oc];
                const int jj = (128 - qi) * rv;
                const int d0 = ((jj + 128) & 255) - 128;
                const int t1 = (jj - d0) >> 8;
                dhl[(size_t)pix * dhlstr + oc] = (signed char)t1;
                dhl[(size_t)pix * dhlstr + 512 + oc] = (signed char)d0;
                dj[(size_t)pix * 512 + oc] = (short)jj;
            } else {
                const int rv = (int)((const short*)res)[(size_t)pix * rstr + oc];
                const int jj = (128 - qi) * rv;
                const int d0 = ((jj + 128) & 255) - 128;
                const int t1 = (jj - d0) >> 8;
                const int d1 = ((t1 + 128) & 255) - 128;
                const int d2 = (t1 - d1) >> 8;
                dhl[(size_t)pix * dhlstr + oc] = (signed char)d2;
                dhl[(size_t)pix * dhlstr + 512 + oc] = (signed char)d1;
                dhl[(size_t)pix * dhlstr + 1024 + oc] = (signed char)d0;
            }
        }
    }
}

// ---------------- implicit-GEMM i8 MFMA conv ----------------
// WM2/WN2 on small-spatial layers: 2 wn-groups halve redundant B-fragment L2 loads,
// TH=8 tiles double block count and cut region waste; smaller LDS lifts residency.
// MODE 0: dst=i8; MODE 2: feat max; MODE 3: i32 partial per slice; MODE 4: atomicAdd.
template<int K, int STR, int WM, int WN, int BN, int CHQ, int NBUF, int MODE>
__global__ void __launch_bounds__(256) k_mconv(
    const signed char* __restrict__ s0, int Ctot, int st0,
    int S, int padeff,
    const uint4* __restrict__ wqp, int nchtot,
    signed char* __restrict__ dst, int dstr, int dch,
    unsigned* __restrict__ feat, int* __restrict__ ps,
    const signed char* __restrict__ zbuf,
    int OCv, int OH, int OW, int TILES_W, int nch,
    int NT, int NOCG, int swzq, int ORD, int ohb, int owb)
{
    constexpr int TH = WM * 4;
    constexpr int RH = (TH - 1) * STR + K, RW = 7 * STR + K;
    constexpr int UNITS = CHQ / 16;
    constexpr int UPPS = UNITS + 1;
    constexpr int NKC = CHQ / 64;
    constexpr int K2 = K * K;
    constexpr int NUS = RH * RW * UPPS;
    constexpr int ROUNDS = (NUS + 255) / 256;
    constexpr int NUPS = ROUNDS * 256;
    constexpr int AHEAD = NBUF - 1;
    __shared__ uint4 lds[NBUF * NUPS];
    __shared__ int sred[4][2][16];

    const int tid = threadIdx.x, lane = tid & 63, w = tid >> 6;
    const int wm = w % WM, wn = w / WM;
    const int l15 = lane & 15, g = lane >> 4;

    const int b = blockIdx.x;
    const int work = (b & 7) * swzq + (b >> 3);
    int tile, n, ocg, slice;
    if (ORD == 0) {
        ocg = work % NOCG; const int t2 = work / NOCG;
        tile = t2 % NT; const int t3 = t2 / NT;
        n = t3 & 7; slice = t3 >> 3;
    } else {
        tile = work % NT; const int t2 = work / NT;
        n = t2 & 7; const int t3 = t2 >> 3;
        ocg = t3 % NOCG; slice = t3 / NOCG;
    }
    const int cin_off = slice * nch * CHQ;
    const int group = ocg * WN + wn;

    const int tileh = tile / TILES_W, tilew = tile % TILES_W;
    const int oh0 = ohb + tileh * TH, ow0 = owb + tilew * 8;
    const int ih0 = oh0 * STR - padeff, iw0 = ow0 * STR - padeff;
    const int blk_oct0 = ocg * (WN * BN);

    int pixb[2];
    #pragma unroll
    for (int am = 0; am < 2; ++am) {
        const int sp = wm * 32 + am * 16 + l15;
        pixb[am] = ((sp >> 3) * STR) * RW + (sp & 7) * STR;
    }

    // hoisted staging addresses: per-rd base pointer + channel-limit
    int climit[ROUNDS];
    const signed char* gpb[ROUNDS];
    #pragma unroll
    for (int rd = 0; rd < ROUNDS; ++rd) {
        const int d = rd * 256 + tid;
        int cl = -1;
        const signed char* gb = zbuf;
        if (d < NUS) {
            const int pix = d / UPPS;
            const int u = d - pix * UPPS;
            const int r = pix / RW, c = pix - r * RW;
            const int ih = ih0 + r, iw = iw0 + c;
            if (u < UNITS && (unsigned)ih < (unsigned)S && (unsigned)iw < (unsigned)S) {
                cl = Ctot - cin_off - u * 16;
                gb = s0 + (((size_t)n * S + ih) * S + iw) * st0 + cin_off + u * 16;
            }
        }
        climit[rd] = cl; gpb[rd] = gb;
    }

    i32x4 acc[2][BN];
    #pragma unroll
    for (int am = 0; am < 2; ++am)
        #pragma unroll
        for (int bn = 0; bn < BN; ++bn) acc[am][bn] = (i32x4){0, 0, 0, 0};

    auto issue = [&](int ch, int buf) {
        uint4* lb = &lds[buf * NUPS];
        const int chv = ch * CHQ;
        #pragma unroll
        for (int rd = 0; rd < ROUNDS; ++rd) {
            const signed char* gp = (chv < climit[rd]) ? (gpb[rd] + chv) : zbuf;
            GLOAD16(gp, lb + rd * 256 + (tid & ~63));
        }
    };

    #pragma unroll
    for (int i = 0; i < AHEAD; ++i) if (i < nch) issue(i, i % NBUF);

    for (int ch = 0; ch < nch; ++ch) {
        if (ch + AHEAD < nch) issue(ch + AHEAD, (ch + AHEAD) % NBUF);
        const int infl = (nch - 1 - ch < AHEAD) ? nch - 1 - ch : AHEAD;
        if (infl >= 2)      __builtin_amdgcn_s_waitcnt(0xF70 | (2 * ROUNDS));
        else if (infl == 1) __builtin_amdgcn_s_waitcnt(0xF70 | ROUNDS);
        else                __builtin_amdgcn_s_waitcnt(0xF70);
        __builtin_amdgcn_s_barrier();
        __builtin_amdgcn_sched_barrier(0);
        const int bufo = (ch % NBUF) * NUPS;
        const int pb0 = bufo + pixb[0] * UPPS + g;
        const int pb1 = bufo + pixb[1] * UPPS + g;
        const uint4* wrow = wqp + ((size_t)(group * nchtot + (slice * nch + ch) * NKC) * K2 * BN) * 64 + lane;
        #pragma unroll
        for (int kpos = 0; kpos < K2; ++kpos) {
            const int kh = kpos / K, kw = kpos % K;
            const int po = (kh * RW + kw) * UPPS;
            #pragma unroll
            for (int kc = 0; kc < NKC; ++kc) {
                i32x4 bfr[BN];
                #pragma unroll
                for (int bn = 0; bn < BN; ++bn) {
                    union { uint4 u; i32x4 v; } bu;
                    bu.u = wrow[(kc * K2 * BN + kpos * BN + bn) * 64];
                    bfr[bn] = bu.v;
                }
                union { uint4 u; i32x4 v; } a0, a1;
                a0.u = lds[pb0 + po + kc * 4];
                a1.u = lds[pb1 + po + kc * 4];
                #pragma unroll
                for (int bn = 0; bn < BN; ++bn) {
                    acc[0][bn] = __builtin_amdgcn_mfma_i32_16x16x64_i8(a0.v, bfr[bn], acc[0][bn], 0, 0, 0);
                    acc[1][bn] = __builtin_amdgcn_mfma_i32_16x16x64_i8(a1.v, bfr[bn], acc[1][bn], 0, 0, 0);
                }
            }
        }
        __builtin_amdgcn_sched_barrier(0);
        __builtin_amdgcn_s_barrier();
    }

    if constexpr (MODE == 2) {
        #pragma unroll
        for (int bn = 0; bn < BN; ++bn) {
            int m = (int)0x80000000;
            #pragma unroll
            for (int am = 0; am < 2; ++am)
                #pragma unroll
                for (int rg = 0; rg < 4; ++rg) {
                    const int sp = wm * 32 + am * 16 + g * 4 + rg;
                    const int oh = oh0 + (sp >> 3), ow = ow0 + (sp & 7);
                    const int v = acc[am][bn][rg];
                    if (oh < OH && ow < OW && v > m) m = v;
                }
            int o = __shfl_xor(m, 16); if (o > m) m = o;
            o = __shfl_xor(m, 32); if (o > m) m = o;
            if (lane < 16) sred[w][bn][l15] = m;
        }
        __syncthreads();
        if (tid < BN * 16) {
            const int bn = tid >> 4, l = tid & 15;
            int mm = sred[0][bn][l];
            #pragma unroll
            for (int i = 1; i < WM * WN; ++i) { const int o = sred[i][bn][l]; if (o > mm) mm = o; }
            const float y = (float)mm * (1.f / 16384.f);
            const float v = (float)wqi(y) * 0.0078125f;
            atomicMax(&feat[n * 32 + (blk_oct0 + bn) * 16 + l], encf(v));
        }
    } else if constexpr (MODE == 3) {
        #pragma unroll
        for (int am = 0; am < 2; ++am)
        #pragma unroll
        for (int bn = 0; bn < BN; ++bn)
        #pragma unroll
        for (int rg = 0; rg < 4; ++rg) {
            const int sp = wm * 32 + am * 16 + g * 4 + rg;
            const int oh = oh0 + (sp >> 3), ow = ow0 + (sp & 7);
            const int oc = (blk_oct0 + wn * BN + bn) * 16 + l15;
            if (oh < OH && ow < OW && oc < OCv) {
                ps[(((size_t)slice * 8 + n) * OH * OW + (size_t)oh * OW + ow) * OCv + oc] = acc[am][bn][rg];
            }
        }
    } else if constexpr (MODE == 4) {
        #pragma unroll
        for (int am = 0; am < 2; ++am)
        #pragma unroll
        for (int bn = 0; bn < BN; ++bn)
        #pragma unroll
        for (int rg = 0; rg < 4; ++rg) {
            const int sp = wm * 32 + am * 16 + g * 4 + rg;
            const int oh = oh0 + (sp >> 3), ow = ow0 + (sp & 7);
            const int oc = (blk_oct0 + wn * BN + bn) * 16 + l15;
            if (oh < OH && ow < OW && oc < OCv) {
                atomicAdd(&ps[((size_t)n * OH * OW + (size_t)oh * OW + ow) * OCv + oc], acc[am][bn][rg]);
            }
        }
    } else {
        #pragma unroll
        for (int am = 0; am < 2; ++am)
        #pragma unroll
        for (int bn = 0; bn < BN; ++bn)
        #pragma unroll
        for (int rg = 0; rg < 4; ++rg) {
            const int sp = wm * 32 + am * 16 + g * 4 + rg;
            const int oh = oh0 + (sp >> 3), ow = ow0 + (sp & 7);
            const int oc = (blk_oct0 + wn * BN + bn) * 16 + l15;
            if (oh < OH && ow < OW && oc < OCv) {
                const size_t pixo = (size_t)(n * OH + oh) * OW + ow;
                const float y = (float)acc[am][bn][rg] * (1.f / 16384.f);
                dst[pixo * dstr + dch + oc] = (signed char)wqi(y);
            }
        }
    }
}

extern "C" void kernel_launch(void* const* d_in, const int* in_sizes, int n_in,
                              void* d_out, int out_size, void* d_ws, size_t ws_size,
                              hipStream_t stream)
{
    (void)in_sizes; (void)n_in; (void)out_size; (void)ws_size;
    const float* x = (const float*)d_in[0];
    const float* wfc = (const float*)d_in[16];
    float* out = (float*)d_out;

    char* ws = (char*)d_ws;
    size_t off = 0;
    auto alloc = [&](size_t bytes) { char* p = ws + off; off += (bytes + 255) & ~(size_t)255; return p; };

    // {w0 idx, OC0, w1 idx, OC1, CinW, K, noct, nch64u, ndup, gsz(=BN)}
    struct PH { int i0, OC0, i1, OC1, CinW, K, noct, nch64u, ndup, gsz; };
    static const PH ph[11] = {
        {2, 128, -1, 0,  64, 3,  8, 1, 1, 2},   // 0 conv2
        {3, 256, -1, 0, 128, 3, 16, 2, 1, 2},   // 1 conv3
        {4, 512, -1, 0, 256, 3, 32, 4, 1, 2},   // 2 conv4
        {5, 512, -1, 0, 512, 3, 32, 8, 1, 2},   // 3 r11
        {6, 512, -1, 0, 512, 3, 32, 8, 1, 2},   // 4 r12
        {7, 512, -1, 0, 512, 3, 32, 8, 2, 2},   // 5 r21 (2 digit copies)
        {8, 512, -1, 0, 512, 3, 32, 8, 1, 2},   // 6 r22
        {9, 128, 12, 32, 512, 4, 12, 8, 3, 2},  // 7 L3 = wd3|wu43 (3 digit copies, noct padded 10->12)
        {10, 64, 13, 32, 416, 4,  6, 7, 1, 2},  // 8 L2 = wd2|wu32
        {11,  4, 14, 32, 224, 4,  3, 4, 1, 3},  // 9 L1 = wd1|wu21 (+12 zero oc)
        {15, 32, -1, 0, 100, 4,  2, 2, 1, 2}};  // 10 u10

    PackArgs pa;
    int bacc = 0;
    uint4* wp[11];
    for (int i = 0; i < 11; ++i) {
        const int nch64 = ph[i].nch64u * ph[i].ndup;
        const int nel = nch64 * ph[i].K * ph[i].K * ph[i].noct * 64;
        wp[i] = (uint4*)alloc((size_t)nel * 16);
        pa.d[i].w0 = (const float*)d_in[ph[i].i0];
        pa.d[i].w1 = (ph[i].i1 >= 0) ? (const float*)d_in[ph[i].i1] : nullptr;
        pa.d[i].dst = wp[i];
        pa.d[i].OC0 = ph[i].OC0; pa.d[i].OC1 = ph[i].OC1;
        pa.d[i].CinW = ph[i].CinW; pa.d[i].K = ph[i].K; pa.d[i].noct = ph[i].noct;
        pa.d[i].nch64u = ph[i].nch64u; pa.d[i].ndup = ph[i].ndup;
        pa.d[i].gsz = ph[i].gsz;
        pa.bofs[i] = bacc;
        bacc += ph[i].noct * ph[i].nch64u;
    }
    pa.bofs[11] = bacc;

    signed char* cat1b = (signed char*)alloc((size_t)8*128*128*112);  // c1|d1|f2|pad12
    signed char* cat2b = (signed char*)alloc((size_t)8*64*64*224);    // c2|d2|f3
    signed char* cat3b = (signed char*)alloc((size_t)8*32*32*416);    // c3|d3|f4
    signed char* c4b   = (signed char*)alloc((size_t)8*16*16*512);
    signed char* r11b  = (signed char*)alloc((size_t)8*16*16*512);    // also r21 out
    signed char* r12d  = (signed char*)alloc((size_t)8*16*16*1024);   // r12 digits hi|lo
    short*       r12j  = (short*)alloc((size_t)8*16*16*512 * 2);      // r12 as i16 j (gate res)
    signed char* r22d  = (signed char*)alloc((size_t)8*16*16*1536);   // r22 digits j2|j1|j0
    int*         psum  = (int*)alloc((size_t)6*8*32*32*160 * 4);      // K-split partials (31.5MB)
    unsigned*    featb = (unsigned*)alloc(256 * 4);
    uint4*       zbuf  = (uint4*)alloc(1024);

    k_packall<<<dim3((unsigned)bacc), dim3(256), 0, stream>>>(pa);
    k_prep<<<dim3(3649), 256, 0, stream>>>(featb, zbuf, (uint4*)psum,
        (uint4*)cat1b, (uint4*)cat2b, (uint4*)cat3b);
    k_conv1<<<dim3(256, 8), dim3(256), 0, stream>>>(x, (const float*)d_in[1], cat1b);

    const signed char* zb = (const signed char*)zbuf;
    const void* nv = nullptr;
    const int BIG = 1 << 30;

    // conv2: cat1 ch0..64 -> cat2 ch0..128   NT=64 NOCG=2 total=1024  ORD0
    k_mconv<3,2,2,2,2,64,1,0><<<dim3(1024), 256, 0, stream>>>(
        cat1b,64,112, 128,1, wp[0],1, cat2b,224,0, nullptr,nullptr, zb,
        128,64,64,8, 1, 64,2,128, 0, 0,0);
    // conv3: cat2 -> cat3 ch0..256           NT=16 NOCG=4 total=512  ORD0
    k_mconv<3,2,2,2,2,64,2,0><<<dim3(512), 256, 0, stream>>>(
        cat2b,128,224, 64,1, wp[1],2, cat3b,416,0, nullptr,nullptr, zb,
        256,32,32,4, 2, 16,4,64, 0, 0,0);
    // conv4 -> atomic psum (4 K-slices)      NT=4 NOCG=8 NSLC=4 total=1024  ORD1
    k_mconv<3,2,2,2,2,64,1,4><<<dim3(1024), 256, 0, stream>>>(
        cat3b,256,416, 32,1, wp[2],4, nullptr,0,0, nullptr,(int*)psum, zb,
        512,16,16,2, 1, 4,8,128, 1, 0,0);
    k_comb<0><<<dim3(1024), 256, 0, stream>>>(psum,1,1, 2048,512, 1.0/16384.0, c4b,512,0, nv,0, nullptr,0,nullptr,
        256,16, 0,BIG,0,BIG, psum);   // zero for r11
    // r11: WM2/WN2, TH=8, NT=4, NOCG=8, 4 atomic K-slices; total=1024 swzq=128 ORD1
    k_mconv<3,1,2,2,2,128,1,4><<<dim3(1024), 256, 0, stream>>>(
        c4b,512,512, 16,1, wp[3],8, nullptr,0,0, nullptr,psum, zb,
        512,16,16,2, 1, 4,8,128, 1, 0,0);
    k_comb<0><<<dim3(1024), 256, 0, stream>>>(psum,1,1, 2048,512, 1.0/16384.0, r11b,512,0, nv,0, nullptr,0,nullptr,
        256,16, 0,BIG,0,BIG, psum);   // zero for r12
    // r12: WM2/WN2, nch=2, 2 atomic K-slices; total=512 swzq=64 ORD1
    k_mconv<3,1,2,2,2,128,1,4><<<dim3(512), 256, 0, stream>>>(
        r11b,512,512, 16,1, wp[4],8, nullptr,0,0, nullptr,psum, zb,
        512,16,16,2, 2, 4,8,64, 1, 0,0);
    k_comb<1><<<dim3(1024), 256, 0, stream>>>(psum,1,1, 2048,512, 1.0/16384.0, nullptr,0,0, c4b,512, r12d,1024,r12j,
        256,16, 0,BIG,0,BIG, nullptr);   // r21 overwrites psum slices
    // r21: WM2/WN2, digits input, nch=2, 4 slices = 2 digits x 2; total=1024 swzq=128 ORD1
    k_mconv<3,1,2,2,2,128,1,3><<<dim3(1024), 256, 0, stream>>>(
        r12d,1024,1024, 16,1, wp[5],16, nullptr,0,0, nullptr,psum, zb,
        512,16,16,2, 2, 4,8,128, 1, 0,0);
    k_comb<0><<<dim3(1024), 256, 0, stream>>>(psum,2,2, 2048,512, 1.0/2097152.0, r11b,512,0, nv,0, nullptr,0,nullptr,
        256,16, 0,BIG,0,BIG, psum);   // zero for r22
    // r22: WM2/WN2, nch=2, 2 atomic K-slices; total=512 swzq=64 ORD1
    k_mconv<3,1,2,2,2,128,1,4><<<dim3(512), 256, 0, stream>>>(
        r11b,512,512, 16,1, wp[6],8, nullptr,0,0, nullptr,psum, zb,
        512,16,16,2, 2, 4,8,64, 1, 0,0);
    k_comb<2><<<dim3(1024), 256, 0, stream>>>(psum,1,1, 2048,512, 1.0/16384.0, nullptr,0,0, r12j,512, r22d,1536,nullptr,
        256,16, 0,BIG,0,BIG, nullptr);
    // L3: WM2/WN2, region [7,25], TH=8: NT=9 (3x3), TILES_W=3, origin (7,7),
    // NOCG=3 (noct padded to 12), 3 digit-slices, nch=4; grid = 9*3*3*8 = 648, swzq=81
    k_mconv<4,1,2,2,2,128,1,3><<<dim3(648), 256, 0, stream>>>(
        r22d,1536,1536, 16,10, wp[7],24, nullptr,0,0, nullptr,psum, zb,
        160,32,32,3, 4, 9,3,81, 1, 7,7);
    k_comb<0><<<dim3(1280), 256, 0, stream>>>(psum,3,1, 8192,160, 1.0/268435456.0, cat3b,416,256, nv,0, nullptr,0,nullptr,
        1024,32, 7,25,7,25, nullptr);
    // L2: [d2|f3], region [15,49]: NT=15 (3x5), TILES_W=5, origin (15,15); grid=360
    k_mconv<4,1,4,1,2,64,2,0><<<dim3(360), 256, 0, stream>>>(
        cat3b,416,416, 32,18, wp[8],7, cat2b,224,128, nullptr,nullptr, zb,
        96,64,64,5, 7, 15,3,45, 0, 15,15);
    // L1: [d1|f2|pad], region [31,97]: NT=45 (5x9), TILES_W=9, origin (31,31); grid=360
    k_mconv<4,1,4,1,3,64,2,0><<<dim3(360), 256, 0, stream>>>(
        cat2b,224,224, 64,34, wp[9],4, cat1b,112,64, nullptr,nullptr, zb,
        48,128,128,9, 4, 45,1,45, 0, 31,31);
    // u10 + fused global max-pool, region [63,197]: NT=153 (9x17), origin (63,63); grid=1224
    k_mconv<4,1,4,1,2,128,1,2><<<dim3(1224), 256, 0, stream>>>(
        cat1b,112,112, 128,66, wp[10],2, nullptr,0,0, featb,nullptr, zb,
        32,257,257,17, 1, 153,1,153, 0, 63,63);
    // FC
    k_fc<<<dim3(1), dim3(64), 0, stream>>>(featb, wfc, out);
}

// Round 21
// 294.521 us; speedup vs baseline: 1.0882x; 1.0008x over previous
//
#include <hip/hip_runtime.h>

#define DEV __device__ __forceinline__

typedef __attribute__((ext_vector_type(4))) int i32x4;

// qi = 128*wq8(y) as int
DEV int wqi(float y) {
    int q = (int)rintf(y * 128.0f);
    return q < -127 ? -127 : (q > 127 ? 127 : q);
}
DEV unsigned encf(float f) { unsigned u = __float_as_uint(f); return (u & 0x80000000u) ? ~u : (u | 0x80000000u); }
DEV float decf(unsigned u) { return (u & 0x80000000u) ? __uint_as_float(u ^ 0x80000000u) : __uint_as_float(~u); }
DEV float wq8f(float x) {
    float q = rintf(x * 128.0f) * 0.0078125f;
    return fminf(fmaxf(q, -0.9921875f), 0.9921875f);
}

// async global->LDS, 16B per lane, dest = uniform base + lane*16 (linear)
#define GLOAD16(g, l) __builtin_amdgcn_global_load_lds( \
    (const __attribute__((address_space(1))) void*)(g), \
    (__attribute__((address_space(3))) void*)(l), 16, 0, 0)

// ---------------- i8 weight pack, LDS-staged coalesced transpose ----------------
struct PackDesc {
    const float* w0; const float* w1; uint4* dst;
    int OC0, OC1, CinW, K, noct, nch64u, ndup, gsz;
};
struct PackArgs { PackDesc d[11]; int bofs[12]; };

__global__ void __launch_bounds__(256) k_packall(PackArgs a) {
    __shared__ unsigned char sb[16 * (64 * 16 + 4)];
    const int b = blockIdx.x;
    int i = 0;
    #pragma unroll
    for (int j = 1; j < 11; ++j) if (b >= a.bofs[j]) i = j;
    const PackDesc D = a.d[i];
    const int b2 = b - a.bofs[i];
    const int oct = b2 % D.noct;
    const int ch64u = b2 / D.noct;
    const int K2 = D.K * D.K;
    const int NCHT = D.nch64u * D.ndup;
    const int row_elems = 64 * K2;
    const int SSTR = row_elems + 4;
    const int QR = row_elems / 4;
    const int NQ = 16 * QR;
    const int cin0 = ch64u * 64;
    const int tid = threadIdx.x;
    const int og = oct / D.gsz, ol = oct % D.gsz;

    for (int q = tid; q < NQ; q += 256) {
        const int r = q / QR, j = q - r * QR;
        const int oc = oct * 16 + r;
        const float* src = nullptr; int oci = 0;
        if (oc < D.OC0) { src = D.w0; oci = oc; }
        else if (oc < D.OC0 + D.OC1) { src = D.w1; oci = oc - D.OC0; }
        const int e0 = j * 4;
        float v[4] = {0.f, 0.f, 0.f, 0.f};
        if (src != nullptr) {
            const float* p = src + ((size_t)oci * D.CinW + cin0) * K2 + e0;
            const int cin_last = cin0 + (e0 + 3) / K2;
            if (cin_last < D.CinW) {
                const float4 f4 = *(const float4*)p;
                v[0] = f4.x; v[1] = f4.y; v[2] = f4.z; v[3] = f4.w;
            } else {
                #pragma unroll
                for (int e = 0; e < 4; ++e) {
                    const int cin = cin0 + (e0 + e) / K2;
                    if (cin < D.CinW) v[e] = p[e];
                }
            }
        }
        unsigned pk = 0;
        #pragma unroll
        for (int e = 0; e < 4; ++e) pk |= ((unsigned)(wqi(v[e]) & 255)) << (e * 8);
        *(unsigned*)&sb[r * SSTR + e0] = pk;
    }
    __syncthreads();

    const int outN = K2 * 64;
    for (int idx = tid; idx < outN; idx += 256) {
        const int kpos = idx >> 6, lane = idx & 63;
        const int l15 = lane & 15, g = lane >> 4;
        unsigned wd[4] = {0u, 0u, 0u, 0u};
        #pragma unroll
        for (int e = 0; e < 16; ++e) {
            const unsigned bval = sb[l15 * SSTR + (g * 16 + e) * K2 + kpos];
            wd[e >> 2] |= bval << ((e & 3) * 8);
        }
        uint4 u; u.x = wd[0]; u.y = wd[1]; u.z = wd[2]; u.w = wd[3];
        for (int d = 0; d < D.ndup; ++d) {
            const int ch64 = ch64u + d * D.nch64u;
            D.dst[((size_t)((og * NCHT + ch64) * K2 + kpos) * D.gsz + ol) * 64 + lane] = u;
        }
    }
}

// ---------------- fused prologue: feat/zbuf init + psum slice0 zero + cat zfills ----------------
__global__ void __launch_bounds__(256) k_prep(unsigned* __restrict__ feat, uint4* __restrict__ zbuf,
                                              uint4* __restrict__ ps0,
                                              uint4* __restrict__ z1, uint4* __restrict__ z2,
                                              uint4* __restrict__ z3) {
    int b = blockIdx.x;
    const int tid = threadIdx.x;
    uint4 z; z.x = z.y = z.z = z.w = 0u;
    if (b == 0) {
        feat[tid] = encf(0.0f);
        if (tid < 64) zbuf[tid] = z;
        return;
    }
    b -= 1;
    if (b < 1024) { ps0[b * 256 + tid] = z; return; }
    b -= 1024;
    if (b < 1536) {
        const int i = b * 256 + tid;
        if (i < 393216) { const int pix = i / 3, j = i - pix * 3; z1[(size_t)pix * 7 + 4 + j] = z; }
        return;
    }
    b -= 1536;
    if (b < 768) {
        const int i = b * 256 + tid;
        if (i < 196608) { const int pix = i / 6, j = i - pix * 6; z2[(size_t)pix * 14 + 8 + j] = z; }
        return;
    }
    b -= 768;
    {
        const int i = b * 256 + tid;
        if (i < 81920) { const int pix = i / 10, j = i - pix * 10; z3[(size_t)pix * 26 + 16 + j] = z; }
    }
}

// ---------------- conv1: LDS-tiled f32 vector conv (exact chain), i8 out ----------------
__global__ void __launch_bounds__(256) k_conv1(const float* __restrict__ x, const float* __restrict__ w1,
                                               signed char* __restrict__ cat1) {
    __shared__ float sw2[36][64];
    __shared__ float sin_[4][17][17];
    const int tid = threadIdx.x;
    const int n = blockIdx.y;
    const int oh0 = (blockIdx.x >> 4) * 8, ow0 = (blockIdx.x & 15) * 8;
    for (int i = tid; i < 2304; i += 256) sw2[i % 36][i / 36] = wq8f(w1[i]);
    const int ih0 = oh0 * 2 - 1, iw0 = ow0 * 2 - 1;
    for (int i = tid; i < 4 * 289; i += 256) {
        const int c = i / 289, rem = i % 289, r = rem / 17, cc = rem % 17;
        const int ih = ih0 + r, iw = iw0 + cc;
        float v = 0.f;
        if ((unsigned)ih < 256u && (unsigned)iw < 256u) v = x[((size_t)(n * 4 + c) * 256 + ih) * 256 + iw];
        sin_[c][r][cc] = v;
    }
    __syncthreads();
    const int sp = tid & 63, ocg = tid >> 6;
    const int oh = sp >> 3, ow = sp & 7;
    float acc[16];
    #pragma unroll
    for (int j = 0; j < 16; ++j) acc[j] = 0.f;
    #pragma unroll
    for (int c = 0; c < 4; ++c)
    #pragma unroll
    for (int kh = 0; kh < 3; ++kh)
    #pragma unroll
    for (int kw = 0; kw < 3; ++kw) {
        const float v = sin_[c][oh * 2 + kh][ow * 2 + kw];
        const float4* wp4 = (const float4*)&sw2[c * 9 + kh * 3 + kw][ocg * 16];
        #pragma unroll
        for (int q = 0; q < 4; ++q) {
            const float4 wv = wp4[q];
            acc[q * 4 + 0] = fmaf(v, wv.x, acc[q * 4 + 0]);
            acc[q * 4 + 1] = fmaf(v, wv.y, acc[q * 4 + 1]);
            acc[q * 4 + 2] = fmaf(v, wv.z, acc[q * 4 + 2]);
            acc[q * 4 + 3] = fmaf(v, wv.w, acc[q * 4 + 3]);
        }
    }
    const size_t pix = ((size_t)(n * 128) + oh0 + oh) * 128 + ow0 + ow;
    unsigned wd[4] = {0u, 0u, 0u, 0u};
    #pragma unroll
    for (int j = 0; j < 16; ++j)
        wd[j >> 2] |= ((unsigned)(wqi(acc[j]) & 255)) << ((j & 3) * 8);
    uint4 u; u.x = wd[0]; u.y = wd[1]; u.z = wd[2]; u.w = wd[3];
    *(uint4*)(cat1 + pix * 112 + ocg * 16) = u;
}

__global__ void k_fc(const unsigned* __restrict__ feat, const float* __restrict__ wfc,
                     float* __restrict__ out) {
    int n = threadIdx.x;
    if (n < 8) {
        float s = 0.f;
        for (int c = 0; c < 32; ++c) s += decf(feat[n * 32 + c]) * wq8f(wfc[c]);
        out[n] = wq8f(s);
    }
}

// ---------------- K-split partial combiner (D digits x G same-scale groups) ----------------
template<int CMODE>
__global__ void __launch_bounds__(256) k_comb(const int* __restrict__ ps, int D, int G,
                                              int NP, int OC, double inv,
                                              signed char* __restrict__ dst, int dstr, int dch,
                                              const void* __restrict__ res, int rstr,
                                              signed char* __restrict__ dhl, int dhlstr,
                                              short* __restrict__ dj,
                                              int ohw, int OWW, int r0, int r1, int c0, int c1,
                                              int* __restrict__ zp) {
    const int t = blockIdx.x * 256 + threadIdx.x;
    const int opc = OC / 4;
    const int total = NP * opc;
    if (t >= total) return;
    const int pix = t / opc, oc0 = (t - pix * opc) * 4;
    const int sp = pix % ohw;
    const int oh = sp / OWW, ow = sp - oh * OWW;
    if (oh < r0 || oh > r1 || ow < c0 || ow > c1) return;
    const size_t base = (size_t)pix * OC + oc0;
    const size_t NPOC = (size_t)NP * OC;
    long v[4] = {0, 0, 0, 0};
    int sidx = 0;
    for (int d = 0; d < D; ++d) {
        long s0 = 0, s1 = 0, s2 = 0, s3 = 0;
        for (int g = 0; g < G; ++g, ++sidx) {
            const int4 p = *(const int4*)(ps + sidx * NPOC + base);
            s0 += p.x; s1 += p.y; s2 += p.z; s3 += p.w;
        }
        v[0] = v[0] * 256 + s0; v[1] = v[1] * 256 + s1;
        v[2] = v[2] * 256 + s2; v[3] = v[3] * 256 + s3;
    }
    if (zp) { int4 z; z.x = z.y = z.z = z.w = 0; *(int4*)(zp + base) = z; }
    if constexpr (CMODE == 0) {
        unsigned pk = 0;
        #pragma unroll
        for (int j = 0; j < 4; ++j)
            pk |= (unsigned)(wqi((float)((double)v[j] * inv)) & 255) << (j * 8);
        *(unsigned*)(dst + (size_t)pix * dstr + dch + oc0) = pk;
    } else {
        #pragma unroll
        for (int j = 0; j < 4; ++j) {
            const int qi = wqi((float)((double)v[j] * inv));
            const int oc = oc0 + j;
            if constexpr (CMODE == 1) {
                const int rv = (int)((const signed char*)res)[(size_t)pix * rstr + oc];
                const int jj = (128 - qi) * rv;
                const int d0 = ((jj + 128) & 255) - 128;
                const int t1 = (jj - d0) >> 8;
                dhl[(size_t)pix * dhlstr + oc] = (signed char)t1;
                dhl[(size_t)pix * dhlstr + 512 + oc] = (signed char)d0;
                dj[(size_t)pix * 512 + oc] = (short)jj;
            } else {
                const int rv = (int)((const short*)res)[(size_t)pix * rstr + oc];
                const int jj = (128 - qi) * rv;
                const int d0 = ((jj + 128) & 255) - 128;
                const int t1 = (jj - d0) >> 8;
                const int d1 = ((t1 + 128) & 255) - 128;
                const int d2 = (t1 - d1) >> 8;
                dhl[(size_t)pix * dhlstr + oc] = (signed char)d2;
                dhl[(size_t)pix * dhlstr + 512 + oc] = (signed char)d1;
                dhl[(size_t)pix * dhlstr + 1024 + oc] = (signed char)d0;
            }
        }
    }
}

// ---------------- implicit-GEMM i8 MFMA conv ----------------
// WM2/WN2 on small-spatial layers; MODE 0: dst=i8; 2: feat max; 3: i32 slice psum;
// 4: atomicAdd psum.
template<int K, int STR, int WM, int WN, int BN, int CHQ, int NBUF, int MODE>
__global__ void __launch_bounds__(256) k_mconv(
    const signed char* __restrict__ s0, int Ctot, int st0,
    int S, int padeff,
    const uint4* __restrict__ wqp, int nchtot,
    signed char* __restrict__ dst, int dstr, int dch,
    unsigned* __restrict__ feat, int* __restrict__ ps,
    const signed char* __restrict__ zbuf,
    int OCv, int OH, int OW, int TILES_W, int nch,
    int NT, int NOCG, int swzq, int ORD, int ohb, int owb)
{
    constexpr int TH = WM * 4;
    constexpr int RH = (TH - 1) * STR + K, RW = 7 * STR + K;
    constexpr int UNITS = CHQ / 16;
    constexpr int UPPS = UNITS + 1;
    constexpr int NKC = CHQ / 64;
    constexpr int K2 = K * K;
    constexpr int NUS = RH * RW * UPPS;
    constexpr int ROUNDS = (NUS + 255) / 256;
    constexpr int NUPS = ROUNDS * 256;
    constexpr int AHEAD = NBUF - 1;
    __shared__ uint4 lds[NBUF * NUPS];
    __shared__ int sred[4][2][16];

    const int tid = threadIdx.x, lane = tid & 63, w = tid >> 6;
    const int wm = w % WM, wn = w / WM;
    const int l15 = lane & 15, g = lane >> 4;

    const int b = blockIdx.x;
    const int work = (b & 7) * swzq + (b >> 3);
    int tile, n, ocg, slice;
    if (ORD == 0) {
        ocg = work % NOCG; const int t2 = work / NOCG;
        tile = t2 % NT; const int t3 = t2 / NT;
        n = t3 & 7; slice = t3 >> 3;
    } else {
        tile = work % NT; const int t2 = work / NT;
        n = t2 & 7; const int t3 = t2 >> 3;
        ocg = t3 % NOCG; slice = t3 / NOCG;
    }
    const int cin_off = slice * nch * CHQ;
    const int group = ocg * WN + wn;

    const int tileh = tile / TILES_W, tilew = tile % TILES_W;
    const int oh0 = ohb + tileh * TH, ow0 = owb + tilew * 8;
    const int ih0 = oh0 * STR - padeff, iw0 = ow0 * STR - padeff;
    const int blk_oct0 = ocg * (WN * BN);

    int pixb[2];
    #pragma unroll
    for (int am = 0; am < 2; ++am) {
        const int sp = wm * 32 + am * 16 + l15;
        pixb[am] = ((sp >> 3) * STR) * RW + (sp & 7) * STR;
    }

    // hoisted staging addresses: per-rd base pointer + channel-limit
    int climit[ROUNDS];
    const signed char* gpb[ROUNDS];
    #pragma unroll
    for (int rd = 0; rd < ROUNDS; ++rd) {
        const int d = rd * 256 + tid;
        int cl = -1;
        const signed char* gb = zbuf;
        if (d < NUS) {
            const int pix = d / UPPS;
            const int u = d - pix * UPPS;
            const int r = pix / RW, c = pix - r * RW;
            const int ih = ih0 + r, iw = iw0 + c;
            if (u < UNITS && (unsigned)ih < (unsigned)S && (unsigned)iw < (unsigned)S) {
                cl = Ctot - cin_off - u * 16;
                gb = s0 + (((size_t)n * S + ih) * S + iw) * st0 + cin_off + u * 16;
            }
        }
        climit[rd] = cl; gpb[rd] = gb;
    }

    i32x4 acc[2][BN];
    #pragma unroll
    for (int am = 0; am < 2; ++am)
        #pragma unroll
        for (int bn = 0; bn < BN; ++bn) acc[am][bn] = (i32x4){0, 0, 0, 0};

    auto issue = [&](int ch, int buf) {
        uint4* lb = &lds[buf * NUPS];
        const int chv = ch * CHQ;
        #pragma unroll
        for (int rd = 0; rd < ROUNDS; ++rd) {
            const signed char* gp = (chv < climit[rd]) ? (gpb[rd] + chv) : zbuf;
            GLOAD16(gp, lb + rd * 256 + (tid & ~63));
        }
    };

    #pragma unroll
    for (int i = 0; i < AHEAD; ++i) if (i < nch) issue(i, i % NBUF);

    for (int ch = 0; ch < nch; ++ch) {
        if (ch + AHEAD < nch) issue(ch + AHEAD, (ch + AHEAD) % NBUF);
        const int infl = (nch - 1 - ch < AHEAD) ? nch - 1 - ch : AHEAD;
        if (infl >= 2)      __builtin_amdgcn_s_waitcnt(0xF70 | (2 * ROUNDS));
        else if (infl == 1) __builtin_amdgcn_s_waitcnt(0xF70 | ROUNDS);
        else                __builtin_amdgcn_s_waitcnt(0xF70);
        __builtin_amdgcn_s_barrier();
        __builtin_amdgcn_sched_barrier(0);
        const int bufo = (ch % NBUF) * NUPS;
        const int pb0 = bufo + pixb[0] * UPPS + g;
        const int pb1 = bufo + pixb[1] * UPPS + g;
        const uint4* wrow = wqp + ((size_t)(group * nchtot + (slice * nch + ch) * NKC) * K2 * BN) * 64 + lane;
        #pragma unroll
        for (int kpos = 0; kpos < K2; ++kpos) {
            const int kh = kpos / K, kw = kpos % K;
            const int po = (kh * RW + kw) * UPPS;
            #pragma unroll
            for (int kc = 0; kc < NKC; ++kc) {
                i32x4 bfr[BN];
                #pragma unroll
                for (int bn = 0; bn < BN; ++bn) {
                    union { uint4 u; i32x4 v; } bu;
                    bu.u = wrow[(kc * K2 * BN + kpos * BN + bn) * 64];
                    bfr[bn] = bu.v;
                }
                union { uint4 u; i32x4 v; } a0, a1;
                a0.u = lds[pb0 + po + kc * 4];
                a1.u = lds[pb1 + po + kc * 4];
                #pragma unroll
                for (int bn = 0; bn < BN; ++bn) {
                    acc[0][bn] = __builtin_amdgcn_mfma_i32_16x16x64_i8(a0.v, bfr[bn], acc[0][bn], 0, 0, 0);
                    acc[1][bn] = __builtin_amdgcn_mfma_i32_16x16x64_i8(a1.v, bfr[bn], acc[1][bn], 0, 0, 0);
                }
            }
        }
        __builtin_amdgcn_sched_barrier(0);
        __builtin_amdgcn_s_barrier();
    }

    if constexpr (MODE == 2) {
        #pragma unroll
        for (int bn = 0; bn < BN; ++bn) {
            int m = (int)0x80000000;
            #pragma unroll
            for (int am = 0; am < 2; ++am)
                #pragma unroll
                for (int rg = 0; rg < 4; ++rg) {
                    const int sp = wm * 32 + am * 16 + g * 4 + rg;
                    const int oh = oh0 + (sp >> 3), ow = ow0 + (sp & 7);
                    const int v = acc[am][bn][rg];
                    if (oh < OH && ow < OW && v > m) m = v;
                }
            int o = __shfl_xor(m, 16); if (o > m) m = o;
            o = __shfl_xor(m, 32); if (o > m) m = o;
            if (lane < 16) sred[w][bn][l15] = m;
        }
        __syncthreads();
        if (tid < BN * 16) {
            const int bn = tid >> 4, l = tid & 15;
            int mm = sred[0][bn][l];
            #pragma unroll
            for (int i = 1; i < WM * WN; ++i) { const int o = sred[i][bn][l]; if (o > mm) mm = o; }
            const float y = (float)mm * (1.f / 16384.f);
            const float v = (float)wqi(y) * 0.0078125f;
            atomicMax(&feat[n * 32 + (blk_oct0 + bn) * 16 + l], encf(v));
        }
    } else if constexpr (MODE == 3) {
        #pragma unroll
        for (int am = 0; am < 2; ++am)
        #pragma unroll
        for (int bn = 0; bn < BN; ++bn)
        #pragma unroll
        for (int rg = 0; rg < 4; ++rg) {
            const int sp = wm * 32 + am * 16 + g * 4 + rg;
            const int oh = oh0 + (sp >> 3), ow = ow0 + (sp & 7);
            const int oc = (blk_oct0 + wn * BN + bn) * 16 + l15;
            if (oh < OH && ow < OW && oc < OCv) {
                ps[(((size_t)slice * 8 + n) * OH * OW + (size_t)oh * OW + ow) * OCv + oc] = acc[am][bn][rg];
            }
        }
    } else if constexpr (MODE == 4) {
        #pragma unroll
        for (int am = 0; am < 2; ++am)
        #pragma unroll
        for (int bn = 0; bn < BN; ++bn)
        #pragma unroll
        for (int rg = 0; rg < 4; ++rg) {
            const int sp = wm * 32 + am * 16 + g * 4 + rg;
            const int oh = oh0 + (sp >> 3), ow = ow0 + (sp & 7);
            const int oc = (blk_oct0 + wn * BN + bn) * 16 + l15;
            if (oh < OH && ow < OW && oc < OCv) {
                atomicAdd(&ps[((size_t)n * OH * OW + (size_t)oh * OW + ow) * OCv + oc], acc[am][bn][rg]);
            }
        }
    } else {
        #pragma unroll
        for (int am = 0; am < 2; ++am)
        #pragma unroll
        for (int bn = 0; bn < BN; ++bn)
        #pragma unroll
        for (int rg = 0; rg < 4; ++rg) {
            const int sp = wm * 32 + am * 16 + g * 4 + rg;
            const int oh = oh0 + (sp >> 3), ow = ow0 + (sp & 7);
            const int oc = (blk_oct0 + wn * BN + bn) * 16 + l15;
            if (oh < OH && ow < OW && oc < OCv) {
                const size_t pixo = (size_t)(n * OH + oh) * OW + ow;
                const float y = (float)acc[am][bn][rg] * (1.f / 16384.f);
                dst[pixo * dstr + dch + oc] = (signed char)wqi(y);
            }
        }
    }
}

extern "C" void kernel_launch(void* const* d_in, const int* in_sizes, int n_in,
                              void* d_out, int out_size, void* d_ws, size_t ws_size,
                              hipStream_t stream)
{
    (void)in_sizes; (void)n_in; (void)out_size; (void)ws_size;
    const float* x = (const float*)d_in[0];
    const float* wfc = (const float*)d_in[16];
    float* out = (float*)d_out;

    char* ws = (char*)d_ws;
    size_t off = 0;
    auto alloc = [&](size_t bytes) { char* p = ws + off; off += (bytes + 255) & ~(size_t)255; return p; };

    // {w0 idx, OC0, w1 idx, OC1, CinW, K, noct, nch64u, ndup, gsz(=BN)}
    struct PH { int i0, OC0, i1, OC1, CinW, K, noct, nch64u, ndup, gsz; };
    static const PH ph[11] = {
        {2, 128, -1, 0,  64, 3,  8, 1, 1, 2},   // 0 conv2
        {3, 256, -1, 0, 128, 3, 16, 2, 1, 2},   // 1 conv3
        {4, 512, -1, 0, 256, 3, 32, 4, 1, 2},   // 2 conv4
        {5, 512, -1, 0, 512, 3, 32, 8, 1, 2},   // 3 r11
        {6, 512, -1, 0, 512, 3, 32, 8, 1, 2},   // 4 r12
        {7, 512, -1, 0, 512, 3, 32, 8, 2, 2},   // 5 r21 (2 digit copies)
        {8, 512, -1, 0, 512, 3, 32, 8, 1, 2},   // 6 r22
        {9, 128, 12, 32, 512, 4, 12, 8, 3, 2},  // 7 L3 = wd3|wu43 (3 digit copies, noct padded 10->12)
        {10, 64, 13, 32, 416, 4,  6, 7, 1, 2},  // 8 L2 = wd2|wu32
        {11,  4, 14, 32, 224, 4,  3, 4, 1, 3},  // 9 L1 = wd1|wu21 (+12 zero oc)
        {15, 32, -1, 0, 100, 4,  2, 2, 1, 2}};  // 10 u10

    PackArgs pa;
    int bacc = 0;
    uint4* wp[11];
    for (int i = 0; i < 11; ++i) {
        const int nch64 = ph[i].nch64u * ph[i].ndup;
        const int nel = nch64 * ph[i].K * ph[i].K * ph[i].noct * 64;
        wp[i] = (uint4*)alloc((size_t)nel * 16);
        pa.d[i].w0 = (const float*)d_in[ph[i].i0];
        pa.d[i].w1 = (ph[i].i1 >= 0) ? (const float*)d_in[ph[i].i1] : nullptr;
        pa.d[i].dst = wp[i];
        pa.d[i].OC0 = ph[i].OC0; pa.d[i].OC1 = ph[i].OC1;
        pa.d[i].CinW = ph[i].CinW; pa.d[i].K = ph[i].K; pa.d[i].noct = ph[i].noct;
        pa.d[i].nch64u = ph[i].nch64u; pa.d[i].ndup = ph[i].ndup;
        pa.d[i].gsz = ph[i].gsz;
        pa.bofs[i] = bacc;
        bacc += ph[i].noct * ph[i].nch64u;
    }
    pa.bofs[11] = bacc;

    signed char* cat1b = (signed char*)alloc((size_t)8*128*128*112);  // c1|d1|f2|pad12
    signed char* cat2b = (signed char*)alloc((size_t)8*64*64*224);    // c2|d2|f3
    signed char* cat3b = (signed char*)alloc((size_t)8*32*32*416);    // c3|d3|f4
    signed char* c4b   = (signed char*)alloc((size_t)8*16*16*512);
    signed char* r11b  = (signed char*)alloc((size_t)8*16*16*512);    // also r21 out
    signed char* r12d  = (signed char*)alloc((size_t)8*16*16*1024);   // r12 digits hi|lo
    short*       r12j  = (short*)alloc((size_t)8*16*16*512 * 2);      // r12 as i16 j (gate res)
    signed char* r22d  = (signed char*)alloc((size_t)8*16*16*1536);   // r22 digits j2|j1|j0
    int*         psum  = (int*)alloc((size_t)6*8*32*32*160 * 4);      // K-split partials (31.5MB)
    unsigned*    featb = (unsigned*)alloc(256 * 4);
    uint4*       zbuf  = (uint4*)alloc(1024);

    k_packall<<<dim3((unsigned)bacc), dim3(256), 0, stream>>>(pa);
    k_prep<<<dim3(3649), 256, 0, stream>>>(featb, zbuf, (uint4*)psum,
        (uint4*)cat1b, (uint4*)cat2b, (uint4*)cat3b);
    k_conv1<<<dim3(256, 8), dim3(256), 0, stream>>>(x, (const float*)d_in[1], cat1b);

    const signed char* zb = (const signed char*)zbuf;
    const void* nv = nullptr;
    const int BIG = 1 << 30;

    // conv2: cat1 ch0..64 -> cat2 ch0..128   NT=64 NOCG=2 total=1024  ORD0
    k_mconv<3,2,2,2,2,64,1,0><<<dim3(1024), 256, 0, stream>>>(
        cat1b,64,112, 128,1, wp[0],1, cat2b,224,0, nullptr,nullptr, zb,
        128,64,64,8, 1, 64,2,128, 0, 0,0);
    // conv3: cat2 -> cat3 ch0..256           NT=16 NOCG=4 total=512  ORD0
    k_mconv<3,2,2,2,2,64,2,0><<<dim3(512), 256, 0, stream>>>(
        cat2b,128,224, 64,1, wp[1],2, cat3b,416,0, nullptr,nullptr, zb,
        256,32,32,4, 2, 16,4,64, 0, 0,0);
    // conv4 -> atomic psum (4 K-slices)      NT=4 NOCG=8 NSLC=4 total=1024  ORD1
    k_mconv<3,2,2,2,2,64,1,4><<<dim3(1024), 256, 0, stream>>>(
        cat3b,256,416, 32,1, wp[2],4, nullptr,0,0, nullptr,(int*)psum, zb,
        512,16,16,2, 1, 4,8,128, 1, 0,0);
    k_comb<0><<<dim3(1024), 256, 0, stream>>>(psum,1,1, 2048,512, 1.0/16384.0, c4b,512,0, nv,0, nullptr,0,nullptr,
        256,16, 0,BIG,0,BIG, psum);   // zero for r11
    // r11: WM2/WN2, TH=8, NT=4, NOCG=8, 4 atomic K-slices; total=1024 swzq=128 ORD1
    k_mconv<3,1,2,2,2,128,1,4><<<dim3(1024), 256, 0, stream>>>(
        c4b,512,512, 16,1, wp[3],8, nullptr,0,0, nullptr,psum, zb,
        512,16,16,2, 1, 4,8,128, 1, 0,0);
    k_comb<0><<<dim3(1024), 256, 0, stream>>>(psum,1,1, 2048,512, 1.0/16384.0, r11b,512,0, nv,0, nullptr,0,nullptr,
        256,16, 0,BIG,0,BIG, psum);   // zero for r12
    // r12: WM2/WN2, nch=2, 2 atomic K-slices; total=512 swzq=64 ORD1
    k_mconv<3,1,2,2,2,128,1,4><<<dim3(512), 256, 0, stream>>>(
        r11b,512,512, 16,1, wp[4],8, nullptr,0,0, nullptr,psum, zb,
        512,16,16,2, 2, 4,8,64, 1, 0,0);
    k_comb<1><<<dim3(1024), 256, 0, stream>>>(psum,1,1, 2048,512, 1.0/16384.0, nullptr,0,0, c4b,512, r12d,1024,r12j,
        256,16, 0,BIG,0,BIG, nullptr);   // r21 overwrites psum slices
    // r21: WM2/WN2, digits input, nch=2, 4 slices = 2 digits x 2; total=1024 swzq=128 ORD1
    k_mconv<3,1,2,2,2,128,1,3><<<dim3(1024), 256, 0, stream>>>(
        r12d,1024,1024, 16,1, wp[5],16, nullptr,0,0, nullptr,psum, zb,
        512,16,16,2, 2, 4,8,128, 1, 0,0);
    k_comb<0><<<dim3(1024), 256, 0, stream>>>(psum,2,2, 2048,512, 1.0/2097152.0, r11b,512,0, nv,0, nullptr,0,nullptr,
        256,16, 0,BIG,0,BIG, psum);   // zero for r22
    // r22: WM2/WN2, nch=2, 2 atomic K-slices; total=512 swzq=64 ORD1
    k_mconv<3,1,2,2,2,128,1,4><<<dim3(512), 256, 0, stream>>>(
        r11b,512,512, 16,1, wp[6],8, nullptr,0,0, nullptr,psum, zb,
        512,16,16,2, 2, 4,8,64, 1, 0,0);
    k_comb<2><<<dim3(1024), 256, 0, stream>>>(psum,1,1, 2048,512, 1.0/16384.0, nullptr,0,0, r12j,512, r22d,1536,nullptr,
        256,16, 0,BIG,0,BIG, nullptr);
    // L3: WM2/WN2, region [7,25], TH=8: NT=9 (3x3), TILES_W=3, origin (7,7),
    // NOCG=3 (noct padded to 12), 6 slices = 3 digits x 2 halves (nch=2, CHQ128);
    // grid = 9*3*6*8 = 1296, swzq=162
    k_mconv<4,1,2,2,2,128,1,3><<<dim3(1296), 256, 0, stream>>>(
        r22d,1536,1536, 16,10, wp[7],24, nullptr,0,0, nullptr,psum, zb,
        160,32,32,3, 2, 9,3,162, 1, 7,7);
    k_comb<0><<<dim3(1280), 256, 0, stream>>>(psum,3,2, 8192,160, 1.0/268435456.0, cat3b,416,256, nv,0, nullptr,0,nullptr,
        1024,32, 7,25,7,25, nullptr);
    // L2: [d2|f3], region [15,49]: NT=15 (3x5), TILES_W=5, origin (15,15); grid=360
    k_mconv<4,1,4,1,2,64,2,0><<<dim3(360), 256, 0, stream>>>(
        cat3b,416,416, 32,18, wp[8],7, cat2b,224,128, nullptr,nullptr, zb,
        96,64,64,5, 7, 15,3,45, 0, 15,15);
    // L1: [d1|f2|pad], region [31,97]: NT=45 (5x9), TILES_W=9, origin (31,31); grid=360
    k_mconv<4,1,4,1,3,64,2,0><<<dim3(360), 256, 0, stream>>>(
        cat2b,224,224, 64,34, wp[9],4, cat1b,112,64, nullptr,nullptr, zb,
        48,128,128,9, 4, 45,1,45, 0, 31,31);
    // u10 + fused global max-pool, region [63,197]: NT=153 (9x17), origin (63,63); grid=1224
    k_mconv<4,1,4,1,2,128,1,2><<<dim3(1224), 256, 0, stream>>>(
        cat1b,112,112, 128,66, wp[10],2, nullptr,0,0, featb,nullptr, zb,
        32,257,257,17, 1, 153,1,153, 0, 63,63);
    // FC
    k_fc<<<dim3(1), dim3(64), 0, stream>>>(featb, wfc, out);
}